// Round 3
// baseline (50.610 us; speedup 1.0000x reference)
//
#include <hip/hip_runtime.h>

// Problem constants (fixed by the reference).
#define T_TABLES 26
#define V_VOCAB  1000
#define D_DIM    128
#define B_BATCH  8192
#define L_BAG    8

#define SEG4   (D_DIM / 4)                 // 32 float4 per 128-float segment
#define ROW4   ((T_TABLES + 1) * SEG4)     // 864 float4 per output row
#define NXCD   8
#define CHUNK  256                         // batch rows per block
#define NCH    (B_BATCH / CHUNK)           // 32 chunks per table
#define GBAG   (T_TABLES * NCH)            // 832 bag-blocks total
#define PERX   (GBAG / NXCD)               // 104 bag-blocks per XCD (exact)
#define DENX   (NCH / NXCD)                // 4 dense chunks per XCD
#define SLOTS  (PERX + DENX)               // 108 slots per XCD

// Work-balanced XCD-pinned assignment: the 832 (table,chunk) bag-blocks form a
// linear list ordered by table; XCD x (blockIdx%8) gets the contiguous run
// [104x, 104x+104) -> exactly 104 gather-blocks per XCD, table L2 footprint
// 4-5 tables (2-2.5 MB < 4 MiB). Boundary tables live on <=2 XCDs.
__global__ __launch_bounds__(256)
void EmbCatDense_53309134078326_kernel(
    const int*   __restrict__ indices,   // [T, B, L] int32
    const float* __restrict__ to_cat,    // [B, D]
    const float* __restrict__ tables,    // [T, V, D]
    float*       __restrict__ out)       // [B, (T+1)*D]
{
    __shared__ int idx_lds[CHUNK * L_BAG];   // 8 KB

    const int bid  = blockIdx.x;
    const int xcd  = bid & (NXCD - 1);
    const int slot = bid >> 3;               // 0..107
    const int tid  = threadIdx.x;
    const int lane = tid & 31;               // float4 column within segment
    const int grp  = tid >> 5;               // 0..7: row group

    if (slot < PERX) {
        // ---- embedding-bag work: linear bag-block g -> (table, chunk) ----
        const int g  = xcd * PERX + slot;
        const int t  = g >> 5;               // g / NCH
        const int c  = g & (NCH - 1);
        const int b0 = c * CHUNK;

        // Stage this chunk's 256*8 indices (8 KB, contiguous) into LDS.
        const int4* ip = reinterpret_cast<const int4*>(
            indices + ((size_t)t * B_BATCH + b0) * L_BAG);
        int4* lp = reinterpret_cast<int4*>(idx_lds);
        lp[tid]       = ip[tid];
        lp[tid + 256] = ip[tid + 256];
        __syncthreads();

        const float4* tb = reinterpret_cast<const float4*>(tables)
                         + (size_t)t * (V_VOCAB * SEG4) + lane;
        float4* o4 = reinterpret_cast<float4*>(out)
                   + (size_t)(t + 1) * SEG4 + lane;

        for (int i = 0; i < CHUNK / 8; ++i) {
            const int j = i * 8 + grp;                 // row within chunk
            float4 acc = make_float4(0.f, 0.f, 0.f, 0.f);
            #pragma unroll
            for (int l = 0; l < L_BAG; ++l) {
                const int r = idx_lds[j * L_BAG + l];  // broadcast in 32-group
                const float4 e = tb[(size_t)r * SEG4]; // 512 B coalesced, L2-hot
                acc.x += e.x; acc.y += e.y; acc.z += e.z; acc.w += e.w;
            }
            o4[(size_t)(b0 + j) * ROW4] = acc;         // full-line write
        }
    } else {
        // ---- dense to_cat copy: 4 chunks per XCD ----
        const int cc = xcd * DENX + (slot - PERX);     // 0..31
        const int b0 = cc * CHUNK;
        const float4* c4 = reinterpret_cast<const float4*>(to_cat) + lane;
        float4* o4 = reinterpret_cast<float4*>(out) + lane;
        for (int i = 0; i < CHUNK / 8; ++i) {
            const size_t j = (size_t)(b0 + i * 8 + grp);
            o4[j * ROW4] = c4[j * SEG4];
        }
    }
}

extern "C" void kernel_launch(void* const* d_in, const int* in_sizes, int n_in,
                              void* d_out, int out_size, void* d_ws, size_t ws_size,
                              hipStream_t stream) {
    const int*   indices = (const int*)  d_in[0];
    // d_in[1] = offsets [T, B] — encodes fixed bag length L, unused.
    const float* to_cat  = (const float*)d_in[2];
    const float* tables  = (const float*)d_in[3];
    float*       out     = (float*)      d_out;

    EmbCatDense_53309134078326_kernel<<<NXCD * SLOTS, 256, 0, stream>>>(
        indices, to_cat, tables, out);
}

// Round 5
// 48.754 us; speedup vs baseline: 1.0381x; 1.0381x over previous
//
#include <hip/hip_runtime.h>

// Problem constants (fixed by the reference).
#define T_TABLES 26
#define V_VOCAB  1000
#define D_DIM    128
#define B_BATCH  8192
#define L_BAG    8

#define SEG4   (D_DIM / 4)                 // 32 float4 per 128-float segment
#define ROW4   ((T_TABLES + 1) * SEG4)     // 864 float4 per output row
#define NXCD   8
#define CHUNK  128                         // batch rows per block
#define NCH    (B_BATCH / CHUNK)           // 64 chunks per table
#define SLOTS  256                         // 4 tables * 64 chunks (xcd 0-1)

// Native vector type: __builtin_nontemporal_* rejects HIP_vector_type<float,4>*
// but accepts clang ext_vector pointers.
typedef float f32x4 __attribute__((ext_vector_type(4)));

// R2 mapping (table t pinned to XCD t%8; beat balanced-run R3), with:
//  - CHUNK 256->128: 2048 blocks (~8/CU) for latency hiding (TLP)
//  - explicit 16-deep load staging per thread (ILP)
//  - nontemporal output stores: keep the 110 MB write stream from evicting
//    the L2-resident tables.
__global__ __launch_bounds__(256)
void EmbCatDense_53309134078326_kernel(
    const int*   __restrict__ indices,   // [T, B, L] int32
    const float* __restrict__ to_cat,    // [B, D]
    const float* __restrict__ tables,    // [T, V, D]
    float*       __restrict__ out)       // [B, (T+1)*D]
{
    __shared__ int idx_lds[CHUNK * L_BAG];   // 4 KB

    const int bid  = blockIdx.x;
    const int xcd  = bid & (NXCD - 1);
    const int slot = bid >> 3;               // 0..255
    const int tid  = threadIdx.x;
    const int lane = tid & 31;               // float4 column within segment
    const int grp  = tid >> 5;               // 0..7: row group

    const int ntab = (xcd < 2) ? 4 : 3;      // #tables t with t%8==xcd, t<26

    if (slot < ntab * NCH) {
        // ---- embedding-bag work: table t, batch rows [b0, b0+CHUNK) ----
        const int t  = xcd + NXCD * (slot >> 6);   // slot / NCH
        const int c  = slot & (NCH - 1);
        const int b0 = c * CHUNK;

        // Stage this chunk's 128*8 indices (4 KB, contiguous) into LDS.
        const int4* ip = reinterpret_cast<const int4*>(
            indices + ((size_t)t * B_BATCH + b0) * L_BAG);
        reinterpret_cast<int4*>(idx_lds)[tid] = ip[tid];
        __syncthreads();

        const f32x4* tb = reinterpret_cast<const f32x4*>(tables)
                        + (size_t)t * (V_VOCAB * SEG4) + lane;
        f32x4* o4 = reinterpret_cast<f32x4*>(out)
                  + (size_t)(t + 1) * SEG4 + lane;

        for (int i = 0; i < CHUNK / 16; ++i) {       // 8 iterations
            const int j0 = i * 16 + grp;             // row pair within chunk
            const int j1 = j0 + 8;

            f32x4 e0[L_BAG], e1[L_BAG];
            #pragma unroll
            for (int l = 0; l < L_BAG; ++l)
                e0[l] = tb[(size_t)idx_lds[j0 * L_BAG + l] * SEG4];
            #pragma unroll
            for (int l = 0; l < L_BAG; ++l)
                e1[l] = tb[(size_t)idx_lds[j1 * L_BAG + l] * SEG4];

            f32x4 a0 = (f32x4)(0.f);
            f32x4 a1 = (f32x4)(0.f);
            #pragma unroll
            for (int l = 0; l < L_BAG; ++l) {
                a0 += e0[l];
                a1 += e1[l];
            }
            __builtin_nontemporal_store(a0, &o4[(size_t)(b0 + j0) * ROW4]);
            __builtin_nontemporal_store(a1, &o4[(size_t)(b0 + j1) * ROW4]);
        }
    } else if (xcd >= 2) {
        // ---- dense to_cat copy: 64 chunks spread over xcd 2..7 ----
        const int spare = slot - 3 * NCH;            // 0..63
        if (spare < 11) {
            const int cc = (xcd - 2) * 11 + spare;
            if (cc < NCH) {
                const int b0 = cc * CHUNK;
                const f32x4* c4 = reinterpret_cast<const f32x4*>(to_cat) + lane;
                f32x4* o4 = reinterpret_cast<f32x4*>(out) + lane;
                for (int i = 0; i < CHUNK / 8; ++i) {
                    const size_t j = (size_t)(b0 + i * 8 + grp);
                    const f32x4 v = __builtin_nontemporal_load(&c4[j * SEG4]);
                    __builtin_nontemporal_store(v, &o4[j * ROW4]);
                }
            }
        }
    }
}

extern "C" void kernel_launch(void* const* d_in, const int* in_sizes, int n_in,
                              void* d_out, int out_size, void* d_ws, size_t ws_size,
                              hipStream_t stream) {
    const int*   indices = (const int*)  d_in[0];
    // d_in[1] = offsets [T, B] — encodes fixed bag length L, unused.
    const float* to_cat  = (const float*)d_in[2];
    const float* tables  = (const float*)d_in[3];
    float*       out     = (float*)      d_out;

    EmbCatDense_53309134078326_kernel<<<NXCD * SLOTS, 256, 0, stream>>>(
        indices, to_cat, tables, out);
}

// Round 6
// 29.090 us; speedup vs baseline: 1.7398x; 1.6760x over previous
//
#include <hip/hip_runtime.h>

// Problem constants (fixed by the reference).
#define T_TABLES 26
#define V_VOCAB  1000
#define D_DIM    128
#define B_BATCH  8192
#define L_BAG    8

#define SEG4   (D_DIM / 4)                   // 32 float4 per 128-float row
#define ROW4   ((T_TABLES + 1) * SEG4)       // 864 float4 per output row
#define NSL    4                             // d-slices per table (32 floats)
#define SL4    (SEG4 / NSL)                  // 8 float4 per slice-row (128 B)
#define NH     2                             // batch halves
#define HB     (B_BATCH / NH)                // 4096 rows per gather block
#define TSLICE (T_TABLES * NSL)              // 104 (t,s) slices
#define GBLK   (TSLICE * NH)                 // 208 gather blocks
#define NBLK   256                           // exactly 1 block per CU
#define NDEN   (NBLK - GBLK)                 // 48 dense-copy blocks
#define DROWS  ((B_BATCH + NDEN - 1) / NDEN) // 171 rows per dense block
#define NTHR   512
#define NWAVE  (NTHR / 64)                   // 8 waves

typedef float f32x4 __attribute__((ext_vector_type(4)));

// L2-gather-BW wall fix: stage each (table, 32-float d-slice) in LDS (125 KB)
// and serve the 872 MB logical gather stream from LDS instead of L2.
// ds_read_b128 pattern r*128 + c*16 covers all 32 banks once per 8-lane
// group -> 8-cycle minimum, conflict-free for ANY random r.
// bid = h*104 + (t*4+s): both batch-halves of a slice share an XCD (104%8==0).
__global__ __launch_bounds__(NTHR)
void EmbCatDense_53309134078326_kernel(
    const int*   __restrict__ indices,   // [T, B, L] int32
    const float* __restrict__ to_cat,    // [B, D]
    const float* __restrict__ tables,    // [T, V, D]
    float*       __restrict__ out)       // [B, (T+1)*D]
{
    __shared__ f32x4 slice[V_VOCAB * SL4];   // 1000 * 128 B = 125 KB

    const int bid = blockIdx.x;
    const int tid = threadIdx.x;

    if (bid < GBLK) {
        // ---- gather block: table t, d-slice s, batch half h ----
        const int h  = bid / TSLICE;
        const int ts = bid - h * TSLICE;
        const int t  = ts >> 2;
        const int s  = ts & 3;
        const int b0 = h * HB;

        // Stage slice: tables[t, :, s*32 .. s*32+32) -> LDS (125 KB).
        const f32x4* tab4 = reinterpret_cast<const f32x4*>(tables)
                          + (size_t)t * (V_VOCAB * SEG4) + s * SL4;
        {
            const int r0 = tid >> 3, cc = tid & 7;   // 64 rows per iter
            #pragma unroll
            for (int it = 0; it < (V_VOCAB + 63) / 64; ++it) {
                const int r = it * 64 + r0;
                if (r < V_VOCAB)
                    slice[r * SL4 + cc] = tab4[(size_t)r * SEG4 + cc];
            }
        }
        __syncthreads();

        const int w    = tid >> 6;       // wave 0..7
        const int lane = tid & 63;
        const int grp  = lane >> 3;      // 8 rows per wave-instr
        const int c    = lane & 7;       // float4 column within slice
        const int* ibase = indices + (size_t)t * B_BATCH * L_BAG;
        f32x4* o4 = reinterpret_cast<f32x4*>(out)
                  + (size_t)(t + 1) * SEG4 + s * SL4 + c;

        #pragma unroll 2
        for (int i = 0; i < HB / (NWAVE * 8); ++i) {      // 64 iters
            const int row = b0 + (i * NWAVE + w) * 8 + grp;
            // All 8 lanes of the group load the row's 8 indices (32 B,
            // broadcast, L1-hot) -> every index is register-resident.
            const int4* ib = reinterpret_cast<const int4*>(
                ibase + (size_t)row * L_BAG);
            const int4 ia = ib[0];
            const int4 iz = ib[1];
            const f32x4 e0 = slice[ia.x * SL4 + c];
            const f32x4 e1 = slice[ia.y * SL4 + c];
            const f32x4 e2 = slice[ia.z * SL4 + c];
            const f32x4 e3 = slice[ia.w * SL4 + c];
            const f32x4 e4 = slice[iz.x * SL4 + c];
            const f32x4 e5 = slice[iz.y * SL4 + c];
            const f32x4 e6 = slice[iz.z * SL4 + c];
            const f32x4 e7 = slice[iz.w * SL4 + c];
            const f32x4 acc = ((e0 + e1) + (e2 + e3)) + ((e4 + e5) + (e6 + e7));
            __builtin_nontemporal_store(acc, &o4[(size_t)row * ROW4]);
        }
    } else {
        // ---- dense to_cat copy: 48 blocks x ~171 rows ----
        const int db = bid - GBLK;
        const long x0 = (long)db * DROWS * SEG4;          // float4 units
        long r1 = (long)(db + 1) * DROWS;
        if (r1 > B_BATCH) r1 = B_BATCH;
        const long x1 = r1 * SEG4;
        const f32x4* c4 = reinterpret_cast<const f32x4*>(to_cat);
        f32x4* o4 = reinterpret_cast<f32x4*>(out);
        for (long x = x0 + tid; x < x1; x += NTHR) {
            const long r = x >> 5;                        // x / SEG4
            const int cc = (int)(x & (SEG4 - 1));
            const f32x4 v = __builtin_nontemporal_load(&c4[x]);
            __builtin_nontemporal_store(v, &o4[r * ROW4 + cc]);
        }
    }
}

extern "C" void kernel_launch(void* const* d_in, const int* in_sizes, int n_in,
                              void* d_out, int out_size, void* d_ws, size_t ws_size,
                              hipStream_t stream) {
    const int*   indices = (const int*)  d_in[0];
    // d_in[1] = offsets [T, B] — encodes fixed bag length L, unused.
    const float* to_cat  = (const float*)d_in[2];
    const float* tables  = (const float*)d_in[3];
    float*       out     = (float*)      d_out;

    EmbCatDense_53309134078326_kernel<<<NBLK, NTHR, 0, stream>>>(
        indices, to_cat, tables, out);
}